// Round 10
// baseline (457840.381 us; speedup 1.0000x reference)
//
#include <hip/hip_runtime.h>
#include <cstdint>
#include <cstddef>

// Problem dims (fixed by setup_inputs)
#define B_   32
#define T_   512
#define D_   1024
#define S_   256
#define M_   10
#define G4   4096   // 4*D
#define K3   3072   // 2*D (x=[inp,ctx]) + D (h)
#define NBLK 256
#define NTHR 256

// out layout: ctx (B,1,D) [32768] | alignment (B,T,S) [4194304] | termination (B,1) [32]
#define AL_OFF   32768
#define TERM_OFF (32768 + (size_t)B_*T_*S_)

#define XS_STRIDE 400

// ---- ablation variants ----
#define VFULL 0   // real kernel: fenced barriers, writes out (REPS=1)
#define VBAR  1   // barrier-only probe: 2 fenced gbars/step, no work
#define VNOF  2   // full work, relaxed (fence-free) barriers, no out writes

// ---------------- grid barrier (two-level, device-scope) ----------------
template<bool FEN>
__device__ __forceinline__ void gbar(unsigned* bar, unsigned g) {
    __syncthreads();
    if (threadIdx.x == 0) {
        if constexpr (FEN) __threadfence();
        const int grp = blockIdx.x & 7;
        unsigned* cnt  = bar + 32*grp;
        unsigned* cntm = bar + 256;
        unsigned* gen  = bar + 512 + 32*grp;
        bool done = false;
        unsigned old;
        if constexpr (FEN)
            old = __hip_atomic_fetch_add(cnt, 1u, __ATOMIC_ACQ_REL, __HIP_MEMORY_SCOPE_AGENT);
        else
            old = __hip_atomic_fetch_add(cnt, 1u, __ATOMIC_RELAXED, __HIP_MEMORY_SCOPE_AGENT);
        if (old == 31u) {
            unsigned old2;
            if constexpr (FEN)
                old2 = __hip_atomic_fetch_add(cntm, 1u, __ATOMIC_ACQ_REL, __HIP_MEMORY_SCOPE_AGENT);
            else
                old2 = __hip_atomic_fetch_add(cntm, 1u, __ATOMIC_RELAXED, __HIP_MEMORY_SCOPE_AGENT);
            if (old2 == 7u) {
                for (int i = 0; i < 8; ++i)
                    __hip_atomic_store(bar + 32*i, 0u, __ATOMIC_RELAXED, __HIP_MEMORY_SCOPE_AGENT);
                __hip_atomic_store(cntm, 0u, __ATOMIC_RELAXED, __HIP_MEMORY_SCOPE_AGENT);
                for (int i = 0; i < 8; ++i) {
                    if constexpr (FEN)
                        __hip_atomic_store(bar + 512 + 32*i, g + 1u, __ATOMIC_RELEASE, __HIP_MEMORY_SCOPE_AGENT);
                    else
                        __hip_atomic_store(bar + 512 + 32*i, g + 1u, __ATOMIC_RELAXED, __HIP_MEMORY_SCOPE_AGENT);
                }
                done = true;
            }
        }
        if (!done) {
            while (__hip_atomic_load(gen, __ATOMIC_RELAXED, __HIP_MEMORY_SCOPE_AGENT) == g)
                __builtin_amdgcn_s_sleep(2);
        }
        if constexpr (FEN) __threadfence();
    }
    __syncthreads();
}

// ---------------- pack: WrecT[k][j] = k<2048 ? W_ih[j][k] : W_hh[j][k-2048] ----------------
__global__ __launch_bounds__(256) void k_pack(const float* __restrict__ Wih,
                                              const float* __restrict__ Whh,
                                              float* __restrict__ WrecT) {
    const int kt = blockIdx.x;   // 0..95
    const int jt = blockIdx.y;   // 0..127
    __shared__ float Tt[32][33];
    const int r = threadIdx.x >> 3;
    const int q = threadIdx.x & 7;
    const int j = jt*32 + r;
    const int k = kt*32 + q*4;
    float4 v;
    if (k < 2048) v = *(const float4*)&Wih[(size_t)j*2048 + k];
    else          v = *(const float4*)&Whh[(size_t)j*1024 + (k - 2048)];
    Tt[r][q*4+0] = v.x; Tt[r][q*4+1] = v.y; Tt[r][q*4+2] = v.z; Tt[r][q*4+3] = v.w;
    __syncthreads();
    float4 o;
    o.x = Tt[q*4+0][r]; o.y = Tt[q*4+1][r]; o.z = Tt[q*4+2][r]; o.w = Tt[q*4+3][r];
    *(float4*)&WrecT[(size_t)(kt*32 + r)*G4 + jt*32 + q*4] = o;
}

// ---------------- bsum + barrier init ----------------
__global__ __launch_bounds__(256) void k_bsum(const float* __restrict__ bih,
                                              const float* __restrict__ bhh,
                                              float* __restrict__ bsum,
                                              unsigned* __restrict__ bar) {
    int i = blockIdx.x*256 + threadIdx.x;
    if (i < G4) bsum[i] = bih[i] + bhh[i];
    if (blockIdx.x == 0)
        for (int j = threadIdx.x; j < 1024; j += 256) bar[j] = 0u;
}

__global__ __launch_bounds__(256) void k_zerobar(unsigned* __restrict__ bar) {
    int i = blockIdx.x*256 + threadIdx.x;
    if (i < 1024) bar[i] = 0u;
}

// ---------------- persistent recurrent kernel (templated for ablation) ----------------
template<int V, int REPS>
__global__ __launch_bounds__(NTHR, 1) void k_rec(
    const float* __restrict__ inp,   // (B,T,D)
    const float* __restrict__ mem,   // (B,S,D)
    const int*   __restrict__ lens,  // (B,)
    const float* __restrict__ Wg,    // (30,1024)
    const float* __restrict__ bg,    // (30,)
    const float* __restrict__ WrecT, // (3072,4096)
    const float* __restrict__ bsum,  // (4096,)
    float* __restrict__ xh,          // (B,2048): [ctx | h]
    float* __restrict__ part,        // (8,B,4096)
    unsigned* __restrict__ bar,
    float* __restrict__ out)
{
    constexpr bool WORK = (V != VBAR);
    constexpr bool FEN  = (V != VNOF);
    constexpr bool OUTW = (V == VFULL);

    __shared__ __align__(16) float Xs[B_*XS_STRIDE];
    __shared__ __align__(16) float hl[D_];
    __shared__ float wl[S_];
    __shared__ float sm[128];
    __shared__ float red[128];
    __shared__ float ksi_l[16];

    const int blk = blockIdx.x;
    const int tid = threadIdx.x;
    const int kc = blk & 7;
    const int jb = blk >> 3;
    const int tk = tid & 7;
    const int tj = tid >> 3;
    const int j0 = jb*128 + tj*4;
    const int b2 = blk & 31;
    const int dc = blk >> 5;
    unsigned bgen = 0;

    float Wreg[192];
    float4 bs4[4];
    float creg[4] = {0.f, 0.f, 0.f, 0.f};
    if constexpr (WORK) {
        const int kb = kc*384 + tk*48;
        #pragma unroll
        for (int kk = 0; kk < 48; ++kk) {
            float4 w4 = *(const float4*)&WrecT[(size_t)(kb + kk)*G4 + j0];
            Wreg[kk*4+0] = w4.x; Wreg[kk*4+1] = w4.y;
            Wreg[kk*4+2] = w4.z; Wreg[kk*4+3] = w4.w;
        }
        #pragma unroll
        for (int g = 0; g < 4; ++g) bs4[g] = *(const float4*)&bsum[g*D_ + tid*4];
        if (blk < B_) for (int i = tid; i < 2*D_; i += NTHR) xh[blk*2*D_ + i] = 0.f;
        if (tid < 16) ksi_l[tid] = 0.f;
    }
    gbar<FEN>(bar, bgen); ++bgen;

    const int colb = tk*48 + 4*((tk>>1)&3);

    for (int rep = 0; rep < REPS; ++rep)
    for (int t = 0; t < T_; ++t) {
        // ================= P1 =================
        if constexpr (WORK) {
            #pragma unroll
            for (int it = 0; it < 12; ++it) {
                int fid = it*NTHR + tid;
                int b   = fid / 96;
                int k4  = fid - b*96;
                int k   = kc*384 + k4*4;
                float4 v;
                if (k < D_) v = *(const float4*)&inp[((size_t)b*T_ + t)*D_ + k];
                else        v = *(const float4*)&xh[b*2*D_ + (k - D_)];
                int col = k4*4 + 4*((k4/24)&3);
                *(float4*)&Xs[b*XS_STRIDE + col] = v;
            }
            __syncthreads();
            for (int bq = 0; bq < 8; ++bq) {
                float acc[4][4] = {{0.f,0.f,0.f,0.f},{0.f,0.f,0.f,0.f},
                                   {0.f,0.f,0.f,0.f},{0.f,0.f,0.f,0.f}};
                const float* x0 = &Xs[(bq*4+0)*XS_STRIDE + colb];
                const float* x1 = &Xs[(bq*4+1)*XS_STRIDE + colb];
                const float* x2 = &Xs[(bq*4+2)*XS_STRIDE + colb];
                const float* x3 = &Xs[(bq*4+3)*XS_STRIDE + colb];
                #pragma unroll
                for (int kq = 0; kq < 12; ++kq) {
                    float4 f0 = *(const float4*)(x0 + kq*4);
                    float4 f1 = *(const float4*)(x1 + kq*4);
                    float4 f2 = *(const float4*)(x2 + kq*4);
                    float4 f3 = *(const float4*)(x3 + kq*4);
                    const float* W0 = &Wreg[kq*16];
                    #pragma unroll
                    for (int jj = 0; jj < 4; ++jj) {
                        float w = W0[jj];
                        acc[0][jj] += f0.x*w; acc[1][jj] += f1.x*w;
                        acc[2][jj] += f2.x*w; acc[3][jj] += f3.x*w;
                    }
                    #pragma unroll
                    for (int jj = 0; jj < 4; ++jj) {
                        float w = W0[4+jj];
                        acc[0][jj] += f0.y*w; acc[1][jj] += f1.y*w;
                        acc[2][jj] += f2.y*w; acc[3][jj] += f3.y*w;
                    }
                    #pragma unroll
                    for (int jj = 0; jj < 4; ++jj) {
                        float w = W0[8+jj];
                        acc[0][jj] += f0.z*w; acc[1][jj] += f1.z*w;
                        acc[2][jj] += f2.z*w; acc[3][jj] += f3.z*w;
                    }
                    #pragma unroll
                    for (int jj = 0; jj < 4; ++jj) {
                        float w = W0[12+jj];
                        acc[0][jj] += f0.w*w; acc[1][jj] += f1.w*w;
                        acc[2][jj] += f2.w*w; acc[3][jj] += f3.w*w;
                    }
                }
                #pragma unroll
                for (int i = 0; i < 4; ++i) {
                    #pragma unroll
                    for (int jj = 0; jj < 4; ++jj) {
                        float v = acc[i][jj];
                        v += __shfl_xor(v, 1);
                        v += __shfl_xor(v, 2);
                        v += __shfl_xor(v, 4);
                        acc[i][jj] = v;
                    }
                }
                if (tk == 0) {
                    #pragma unroll
                    for (int i = 0; i < 4; ++i) {
                        int b = bq*4 + i;
                        *(float4*)&part[(size_t)(kc*B_ + b)*G4 + j0] =
                            make_float4(acc[i][0], acc[i][1], acc[i][2], acc[i][3]);
                    }
                }
            }
        }
        gbar<FEN>(bar, bgen); ++bgen;

        // ================= P2 (replicated) + P3 (fused) =================
        if constexpr (WORK) {
            {
                const int d4 = tid*4;
                float hv[4];
                float ga[4][4];
                #pragma unroll
                for (int g = 0; g < 4; ++g) {
                    float4 s = bs4[g];
                    #pragma unroll
                    for (int kc2 = 0; kc2 < 8; ++kc2) {
                        float4 p = *(const float4*)&part[(size_t)(kc2*B_ + b2)*G4 + g*D_ + d4];
                        s.x += p.x; s.y += p.y; s.z += p.z; s.w += p.w;
                    }
                    ga[g][0] = s.x; ga[g][1] = s.y; ga[g][2] = s.z; ga[g][3] = s.w;
                }
                #pragma unroll
                for (int i = 0; i < 4; ++i) {
                    float ig = 1.f/(1.f + expf(-ga[0][i]));
                    float fg = 1.f/(1.f + expf(-ga[1][i]));
                    float gg = tanhf(ga[2][i]);
                    float og = 1.f/(1.f + expf(-ga[3][i]));
                    float cn = fg*creg[i] + ig*gg;
                    creg[i] = cn;
                    hv[i] = og*tanhf(cn);
                }
                *(float4*)&hl[d4] = make_float4(hv[0], hv[1], hv[2], hv[3]);
                if (blk < B_) *(float4*)&xh[b2*2*D_ + D_ + d4] = make_float4(hv[0], hv[1], hv[2], hv[3]);
            }
            __syncthreads();
            {
                int m = tid >> 3, l = tid & 7;
                if (m < 30) {
                    float a = 0.f;
                    const float* wgp = &Wg[m*D_];
                    for (int d0 = l; d0 < D_; d0 += 8) a += hl[d0]*wgp[d0];
                    a += __shfl_down(a, 4, 8);
                    a += __shfl_down(a, 2, 8);
                    a += __shfl_down(a, 1, 8);
                    if (l == 0) sm[m] = a + bg[m];
                }
            }
            __syncthreads();
            if (tid < M_) {
                sm[32+tid] = expf(sm[20+tid]);
                float kn = fminf(ksi_l[tid] + expf(sm[tid]), (float)(S_-1));
                ksi_l[tid] = kn;
                sm[48+tid] = kn;
                sm[64+tid] = expf(sm[10+tid]);
            }
            if (tid == 0) {
                float se = 0.f;
                #pragma unroll
                for (int mm = 0; mm < M_; ++mm) se += expf(sm[20+mm]);
                sm[88] = se;
            }
            __syncthreads();
            {
                int s = tid;
                float t1 = 0.f, t2 = 0.f;
                #pragma unroll
                for (int mm = 0; mm < M_; ++mm) {
                    float a = sm[32+mm], kk2 = sm[48+mm], be = sm[64+mm];
                    float xr = ((float)s + 0.5f - kk2)/be;
                    float xl = ((float)s - 0.5f - kk2)/be;
                    t1 += a/(1.f + expf(-xr));
                    t2 += a/(1.f + expf(-xl));
                }
                float wraw = t1 - t2;
                float v = wraw;
                v += __shfl_down(v, 32); v += __shfl_down(v, 16); v += __shfl_down(v, 8);
                v += __shfl_down(v, 4);  v += __shfl_down(v, 2);  v += __shfl_down(v, 1);
                if ((tid & 63) == 0) sm[96 + (tid >> 6)] = v;
                __syncthreads();
                float wsum = sm[96] + sm[97] + sm[98] + sm[99];
                float w = wraw / wsum;
                wl[s] = w;
                if constexpr (OUTW) {
                    if (blk < B_) {
                        out[AL_OFF + ((size_t)b2*T_ + t)*S_ + s] = w;
                        if (t == T_-1) {
                            int idx = lens[b2] - 1;
                            idx = idx < 0 ? 0 : (idx > S_-1 ? S_-1 : idx);
                            if (s == idx) out[TERM_OFF + b2] = 1.f - t1/sm[88];
                        }
                    }
                }
            }
            __syncthreads();
            {
                const int dd = tid & 127;
                const int sh = tid >> 7;
                const int d  = dc*128 + dd;
                const float* mp = mem + ((size_t)b2*S_ + sh*128)*D_ + d;
                float a3 = 0.f;
                #pragma unroll 8
                for (int s2 = 0; s2 < 128; ++s2) a3 += wl[sh*128 + s2]*mp[(size_t)s2*D_];
                if (sh) red[dd] = a3;
                __syncthreads();
                if (!sh) {
                    float v = a3 + red[dd];
                    xh[b2*2*D_ + d] = v;
                    if constexpr (OUTW) { if (t == T_-1) out[(size_t)b2*D_ + d] = v; }
                }
            }
        }
        gbar<FEN>(bar, bgen); ++bgen;
    }
}

// ---------------- host ----------------
extern "C" void kernel_launch(void* const* d_in, const int* in_sizes, int n_in,
                              void* d_out, int out_size, void* d_ws, size_t ws_size,
                              hipStream_t stream) {
    const float* inp  = (const float*)d_in[0];
    const float* mem  = (const float*)d_in[1];
    const int*   lens = (const int*)  d_in[2];
    const float* Wih  = (const float*)d_in[3];
    const float* Whh  = (const float*)d_in[4];
    const float* bih  = (const float*)d_in[5];
    const float* bhh  = (const float*)d_in[6];
    const float* Wg   = (const float*)d_in[7];
    const float* bg   = (const float*)d_in[8];
    float* out = (float*)d_out;

    float* WrecT = (float*)d_ws;                    // 3072*4096
    float* part  = WrecT + (size_t)K3*G4;           // 8*32*4096
    float* xh    = part + (size_t)8*B_*G4;          // 32*2048
    float* bsum  = xh + (size_t)B_*2*D_;            // 4096
    unsigned* bar = (unsigned*)(bsum + G4);         // 1024 u32
    size_t need = (size_t)((char*)(bar + 1024) - (char*)d_ws);
    if (ws_size < need) return;

    k_pack<<<dim3(96,128), dim3(256), 0, stream>>>(Wih, Whh, WrecT);
    k_bsum<<<dim3(16), dim3(256), 0, stream>>>(bih, bhh, bsum, bar);

    // ---- real kernel (correctness + anchor) ----
    void* args[] = { (void*)&inp, (void*)&mem, (void*)&lens, (void*)&Wg, (void*)&bg,
                     (void*)&WrecT, (void*)&bsum, (void*)&xh,
                     (void*)&part, (void*)&bar, (void*)&out };
    hipError_t e = hipLaunchCooperativeKernel((void*)k_rec<VFULL,1>, dim3(NBLK), dim3(NTHR),
                                              args, 0, stream);
    if (e != hipSuccess) {
        // Plain launch is safe: __launch_bounds__(256,1) + 57.4KB LDS => exactly
        // 1 block/CU, grid==256==#CUs => co-resident (round-9 proven path).
        k_rec<VFULL,1><<<dim3(NBLK), dim3(NTHR), 0, stream>>>(
            inp, mem, lens, Wg, bg, WrecT, bsum, xh, part, bar, out);
    }

    // ---- ablation probe 1: pure barrier floor, x16 steps (8192 fenced pairs) ----
    k_zerobar<<<dim3(4), dim3(256), 0, stream>>>(bar);
    k_rec<VBAR,16><<<dim3(NBLK), dim3(NTHR), 0, stream>>>(
        inp, mem, lens, Wg, bg, WrecT, bsum, xh, part, bar, out);

    // ---- ablation probe 2: full work, fence-free relaxed barriers, x4 steps ----
    // (results are scratch-only: no out writes; races across XCDs are benign)
    k_zerobar<<<dim3(4), dim3(256), 0, stream>>>(bar);
    k_rec<VNOF,4><<<dim3(NBLK), dim3(NTHR), 0, stream>>>(
        inp, mem, lens, Wg, bg, WrecT, bsum, xh, part, bar, out);
}